// Round 15
// baseline (173.559 us; speedup 1.0000x reference)
//
#include <hip/hip_runtime.h>
#include <math.h>

#define N_USERS 40000
#define N_ITEMS 20000
#define NNODES  60000          // N_USERS + N_ITEMS; also the zero-pad row index
#define D       128
#define N_EDGES 320000
#define EPS_    1e-7f
#define BATCH   4096
#define STRIDE  64             // ELL row capacity (max degree ~45 for Poisson(16))
#define ZSCALE  256.0f         // fp8 storage scale; folded out in bpr
#define BPR_BLOCKS (BATCH / 8)             // 512: 4 waves x 2 elements each
#define FILL_GRPS  320                     // blocks per bucket
#define FILL_BLOCKS (8 * FILL_GRPS)        // 2560
#define INIT_BLOCKS (((NNODES + 1) * 16 + 255) / 256)  // 3751 (16 thr/row, +pad row)
#define USER_BLOCKS (N_USERS * 8 / 256)    // 1250
#define ITEM_BLOCKS (N_ITEMS * 8 / 256)    // 625

typedef float vf2 __attribute__((ext_vector_type(2)));

// unpack 16 fp8 (e4m3) from uint4, accumulate into 8 packed-f32 pairs.
__device__ __forceinline__ void add_fp8x16v(vf2* a, uint4 t) {
    a[0] += __builtin_amdgcn_cvt_pk_f32_fp8(t.x, false);
    a[1] += __builtin_amdgcn_cvt_pk_f32_fp8(t.x, true);
    a[2] += __builtin_amdgcn_cvt_pk_f32_fp8(t.y, false);
    a[3] += __builtin_amdgcn_cvt_pk_f32_fp8(t.y, true);
    a[4] += __builtin_amdgcn_cvt_pk_f32_fp8(t.z, false);
    a[5] += __builtin_amdgcn_cvt_pk_f32_fp8(t.z, true);
    a[6] += __builtin_amdgcn_cvt_pk_f32_fp8(t.w, false);
    a[7] += __builtin_amdgcn_cvt_pk_f32_fp8(t.w, true);
}

// scale + clamp + pack 8 vf2 (16 f32) -> 16 fp8 (e4m3) in uint4
__device__ __forceinline__ uint4 pack_fp8x16v(const vf2* a, float w) {
    float v[16];
    #pragma unroll
    for (int k = 0; k < 8; ++k) {
        v[2 * k]     = fminf(fmaxf(w * a[k].x, -448.0f), 448.0f);
        v[2 * k + 1] = fminf(fmaxf(w * a[k].y, -448.0f), 448.0f);
    }
    int w0 = __builtin_amdgcn_cvt_pk_fp8_f32(v[0],  v[1],  0,  false);
    w0     = __builtin_amdgcn_cvt_pk_fp8_f32(v[2],  v[3],  w0, true);
    int w1 = __builtin_amdgcn_cvt_pk_fp8_f32(v[4],  v[5],  0,  false);
    w1     = __builtin_amdgcn_cvt_pk_fp8_f32(v[6],  v[7],  w1, true);
    int w2 = __builtin_amdgcn_cvt_pk_fp8_f32(v[8],  v[9],  0,  false);
    w2     = __builtin_amdgcn_cvt_pk_fp8_f32(v[10], v[11], w2, true);
    int w3 = __builtin_amdgcn_cvt_pk_fp8_f32(v[12], v[13], 0,  false);
    w3     = __builtin_amdgcn_cvt_pk_fp8_f32(v[14], v[15], w3, true);
    uint4 o; o.x = (unsigned)w0; o.y = (unsigned)w1;
    o.z = (unsigned)w2; o.w = (unsigned)w3;
    return o;
}

// gather 8 padded edges (2 int4 col loads, 8 uint4 gathers all in flight)
__device__ __forceinline__ void gather8(const int4* __restrict__ rcv, int t,
                                        const uint4* __restrict__ z, int sub,
                                        vf2* a) {
    int4 ca = rcv[2 * t], cb = rcv[2 * t + 1];
    uint4 t0 = z[(ca.x << 3) + sub];
    uint4 t1 = z[(ca.y << 3) + sub];
    uint4 t2 = z[(ca.z << 3) + sub];
    uint4 t3 = z[(ca.w << 3) + sub];
    uint4 t4 = z[(cb.x << 3) + sub];
    uint4 t5 = z[(cb.y << 3) + sub];
    uint4 t6 = z[(cb.z << 3) + sub];
    uint4 t7 = z[(cb.w << 3) + sub];
    add_fp8x16v(a, t0); add_fp8x16v(a, t1);
    add_fp8x16v(a, t2); add_fp8x16v(a, t3);
    add_fp8x16v(a, t4); add_fp8x16v(a, t5);
    add_fp8x16v(a, t6); add_fp8x16v(a, t7);
}

// ---- bucketed ELL fill (int2-vectorized); fillc ends holding the degree --
// users: bucket = u/10000 (0..3); items: bucket = 4 + (i-N_USERS)/5000.
__global__ void fill_ell(const int2* __restrict__ au2, const int2* __restrict__ ai2,
                         int* __restrict__ fillc, int* __restrict__ colell) {
    const int bucket = blockIdx.x & 7;
    const int grp    = blockIdx.x >> 3;          // 0..FILL_GRPS-1
    const int NE2    = N_EDGES / 2;
    for (int i = grp * 256 + threadIdx.x; i < NE2; i += FILL_GRPS * 256) {
        int2 us = au2[i];
        int2 is = ai2[i];
        int u0 = us.x, i0 = N_USERS + is.x;
        int u1 = us.y, i1 = N_USERS + is.y;
        if (u0 / 10000 == bucket) {
            int pos = atomicAdd(&fillc[u0], 1);
            if (pos < STRIDE) colell[(u0 << 6) + pos] = i0;
        }
        if (u1 / 10000 == bucket) {
            int pos = atomicAdd(&fillc[u1], 1);
            if (pos < STRIDE) colell[(u1 << 6) + pos] = i1;
        }
        if (4 + (i0 - N_USERS) / 5000 == bucket) {
            int pos = atomicAdd(&fillc[i0], 1);
            if (pos < STRIDE) colell[(i0 << 6) + pos] = u0;
        }
        if (4 + (i1 - N_USERS) / 5000 == bucket) {
            int pos = atomicAdd(&fillc[i1], 1);
            if (pos < STRIDE) colell[(i1 << 6) + pos] = u1;
        }
    }
}

// ---- z0 init + colell 8-padding + zero-row init --------------------------
// 16 threads per row. Row NNODES is the shared zero row of z0/z1/z2.
__global__ void init_z(const int* __restrict__ fillc,
                       const float4* __restrict__ ue, const float4* __restrict__ ie,
                       uint2* __restrict__ z0, uint2* __restrict__ z1,
                       uint2* __restrict__ z2, int* __restrict__ colell) {
    int i   = blockIdx.x * 256 + threadIdx.x;
    if (i >= (NNODES + 1) * 16) return;
    int row = i >> 4;
    int sub = i & 15;
    if (row == NNODES) {                 // zero-pad row in all three buffers
        uint2 zz = make_uint2(0u, 0u);
        z0[i] = zz; z1[i] = zz; z2[i] = zz;
        return;
    }
    int e = fillc[row];
    if (sub == 0) {                      // pad colell row to a multiple of 8
        int ep = (e + 7) & ~7;
        for (int k = e; k < ep; ++k) colell[(row << 6) + k] = NNODES;
    }
    float w = rsqrtf((float)e + EPS_) * ZSCALE;
    float4 e0, e1;
    if (row < N_USERS) {
        int b4 = row * 32 + sub * 2;     // 32 float4 per row
        e0 = ue[b4]; e1 = ue[b4 + 1];
    } else {
        int b4 = (row - N_USERS) * 32 + sub * 2;
        e0 = ie[b4]; e1 = ie[b4 + 1];
    }
    float v[8] = { e0.x * w, e0.y * w, e0.z * w, e0.w * w,
                   e1.x * w, e1.y * w, e1.z * w, e1.w * w };
    float c[8];
    #pragma unroll
    for (int k = 0; k < 8; ++k) c[k] = fminf(fmaxf(v[k], -448.0f), 448.0f);
    int lo = __builtin_amdgcn_cvt_pk_fp8_f32(c[0], c[1], 0,  false);
    lo     = __builtin_amdgcn_cvt_pk_fp8_f32(c[2], c[3], lo, true);
    int hi = __builtin_amdgcn_cvt_pk_fp8_f32(c[4], c[5], 0,  false);
    hi     = __builtin_amdgcn_cvt_pk_fp8_f32(c[6], c[7], hi, true);
    z0[i] = make_uint2((unsigned)lo, (unsigned)hi);
}

// ---- SpMM, 8-lane subgroup rows, 8-edge padded chunks --------------------
// Bipartite phase split: user rows gather only the 2.56MB item region
// (fits each XCD's 4MB L2); item rows gather only the 5.12MB user region.
__device__ __forceinline__ void spmm_body(int row0,
                                          const int* __restrict__ cnt,
                                          const int* __restrict__ colell,
                                          const uint4* __restrict__ z,
                                          uint4* __restrict__ znxt) {
    int tid = blockIdx.x * 256 + threadIdx.x;
    int row = row0 + (tid >> 3);      // 32 rows per 256-thread block
    int sub = threadIdx.x & 7;
    int e = cnt[row];
    const int4* rcv = (const int4*)(colell + (row << 6));
    vf2 a[8];
    #pragma unroll
    for (int k = 0; k < 8; ++k) a[k] = (vf2)(0.0f);
    int nchunks = (e + 7) >> 3;
    for (int t = 0; t < nchunks; ++t) gather8(rcv, t, z, sub, a);
    float w = 1.0f / ((float)e + EPS_);   // dinv^2
    znxt[(row << 3) + sub] = pack_fp8x16v(a, w);
}

__global__ void spmm_users(const int* __restrict__ cnt, const int* __restrict__ colell,
                           const uint4* __restrict__ z, uint4* __restrict__ znxt) {
    spmm_body(0, cnt, colell, z, znxt);
}
__global__ void spmm_items(const int* __restrict__ cnt, const int* __restrict__ colell,
                           const uint4* __restrict__ z, uint4* __restrict__ znxt) {
    spmm_body(N_USERS, cnt, colell, z, znxt);
}

// ---- fused BPR loss: 2 elements per wave; u/p/n rows in 8-lane subgroups
// sg 0-2 = elem A's u/p/n, sg 4-6 = elem B's; sg 3/7 idle.
// zsum = dinv*ZSCALE*emb (f32 exact) + z1 + z2 + inline layer-3 from z2.
// diff = (sp/(du*dp) - sn/(du*dn)) / (16 * ZSCALE^2)
__global__ void bpr_loss(const float4* __restrict__ ue, const float4* __restrict__ ie,
                         const uint4* __restrict__ z1, const uint4* __restrict__ z2,
                         const int* __restrict__ cnt, const int* __restrict__ colell,
                         const int* __restrict__ user, const int* __restrict__ pos,
                         const int* __restrict__ neg,
                         float* __restrict__ lacc, int* __restrict__ done,
                         float* __restrict__ out) {
    __shared__ float s[8];
    int wave = (blockIdx.x * 256 + threadIdx.x) >> 6;   // global wave id
    int lane = threadIdx.x & 63;
    int sg   = lane >> 3;          // 0..7
    int sub  = lane & 7;
    int half = sg >> 2;            // 0 = elem A, 1 = elem B
    int sgl  = sg & 3;             // 0=u 1=p 2=n 3=idle
    int el   = wave * 2 + half;
    int u = user[el];
    int p = N_USERS + pos[el] - 1;  // 1-indexed items
    int n = N_USERS + neg[el] - 1;
    int node = (sgl == 1) ? p : (sgl == 2) ? n : u;
    float cnode = 0.0f;
    vf2 vals[8];
    #pragma unroll
    for (int k = 0; k < 8; ++k) vals[k] = (vf2)(0.0f);
    if (sgl < 3) {
        int e = cnt[node];
        cnode = (float)e;
        // layer-0 exact from f32 embeddings: 4 float4 per lane
        const float4* eb = (node < N_USERS) ? ue : ie;
        int b4 = ((node < N_USERS) ? node : node - N_USERS) * 32 + sub * 4;
        float4 e0 = eb[b4], e1 = eb[b4 + 1], e2 = eb[b4 + 2], e3 = eb[b4 + 3];
        float w0 = rsqrtf(cnode + EPS_) * ZSCALE;
        vals[0] = (vf2){w0 * e0.x, w0 * e0.y}; vals[1] = (vf2){w0 * e0.z, w0 * e0.w};
        vals[2] = (vf2){w0 * e1.x, w0 * e1.y}; vals[3] = (vf2){w0 * e1.z, w0 * e1.w};
        vals[4] = (vf2){w0 * e2.x, w0 * e2.y}; vals[5] = (vf2){w0 * e2.z, w0 * e2.w};
        vals[6] = (vf2){w0 * e3.x, w0 * e3.y}; vals[7] = (vf2){w0 * e3.z, w0 * e3.w};
        int o = (node << 3) + sub;
        add_fp8x16v(vals, z1[o]);
        add_fp8x16v(vals, z2[o]);
        // inline layer-3 gather from z2 (f32), 8-edge padded chunks
        const int4* rcv = (const int4*)(colell + (node << 6));
        vf2 a[8];
        #pragma unroll
        for (int k = 0; k < 8; ++k) a[k] = (vf2)(0.0f);
        int nchunks = (e + 7) >> 3;
        for (int t = 0; t < nchunks; ++t) gather8(rcv, t, z2, sub, a);
        float w2 = 1.0f / (cnode + EPS_);   // dinv^2
        #pragma unroll
        for (int k = 0; k < 8; ++k) vals[k] += w2 * a[k];
    }
    // pull the u-subgroup (sg0 / sg4) values into all subgroups of the half
    int usrc = sub | (lane & 32);
    float dotp = 0.0f;
    #pragma unroll
    for (int k = 0; k < 8; ++k) {
        dotp += __shfl(vals[k].x, usrc) * vals[k].x;
        dotp += __shfl(vals[k].y, usrc) * vals[k].y;
    }
    dotp += __shfl_down(dotp, 4, 8);
    dotp += __shfl_down(dotp, 2, 8);
    dotp += __shfl_down(dotp, 1, 8);
    // subgroup heads now hold: lane (lane&32)+8 -> u.p, +16 -> u.n
    float sp = __shfl(dotp, (lane & 32) + 8);
    float sn = __shfl(dotp, (lane & 32) + 16);
    float cu = __shfl(cnode, (lane & 32) + 0);
    float cp = __shfl(cnode, (lane & 32) + 8);
    float cn = __shfl(cnode, (lane & 32) + 16);
    if ((lane & 31) == 0) {   // lane 0 (elem A) and lane 32 (elem B)
        float du = rsqrtf(cu + EPS_), dp = rsqrtf(cp + EPS_), dn = rsqrtf(cn + EPS_);
        const float inv = 1.0f / (16.0f * ZSCALE * ZSCALE);
        float diff = (sp / (du * dp) - sn / (du * dn)) * inv;
        // log_sigmoid(x) = min(x,0) - log1p(exp(-|x|))
        s[(threadIdx.x >> 6) * 2 + half] =
            fminf(diff, 0.0f) - log1pf(expf(-fabsf(diff)));
    }
    __syncthreads();
    if (threadIdx.x == 0) {
        float t = s[0] + s[1] + s[2] + s[3] + s[4] + s[5] + s[6] + s[7];
        atomicAdd(lacc, t);
        __threadfence();
        int prev = atomicAdd(done, 1);
        if (prev == BPR_BLOCKS - 1) {
            float total = atomicAdd(lacc, 0.0f);   // coherent read
            out[0] = -total * (1.0f / (float)BATCH);
        }
    }
}

extern "C" void kernel_launch(void* const* d_in, const int* in_sizes, int n_in,
                              void* d_out, int out_size, void* d_ws, size_t ws_size,
                              hipStream_t stream) {
    const float* ue  = (const float*)d_in[0];
    const float* ie  = (const float*)d_in[1];
    const int*   au  = (const int*)d_in[2];
    const int*   ai  = (const int*)d_in[3];
    const int*   usr = (const int*)d_in[4];
    const int*   pos = (const int*)d_in[5];
    const int*   neg = (const int*)d_in[6];
    float*       out = (float*)d_out;

    const size_t ZQ4 = (size_t)(NNODES + 1) * 8;  // uint4 per z buffer (+zero row)

    // ws layout (16B-aligned chunks):
    // z0 | z1 | z2 (fp8, NNODES+1 rows) | [fillc | lacc | done | pad] | colell
    uint4* z0     = (uint4*)d_ws;
    uint4* z1     = z0 + ZQ4;
    uint4* z2     = z1 + ZQ4;
    int*   fillc  = (int*)(z2 + ZQ4);
    float* lacc   = (float*)(fillc + NNODES);
    int*   done   = (int*)(lacc + 1);
    int*   colell = (int*)(lacc + 4);             // NNODES * STRIDE ints

    // fillc + lacc + done zeroed in one shot
    hipMemsetAsync(fillc, 0, (NNODES + 4) * sizeof(int), stream);

    fill_ell<<<FILL_BLOCKS, 256, 0, stream>>>((const int2*)au, (const int2*)ai,
                                              fillc, colell);
    init_z<<<INIT_BLOCKS, 256, 0, stream>>>(fillc, (const float4*)ue,
                                            (const float4*)ie, (uint2*)z0,
                                            (uint2*)z1, (uint2*)z2, colell);

    // bipartite phase-split propagation: each phase's gather region fits
    // (mostly) in a single XCD's 4MB L2, avoiding 8-way replication misses.
    spmm_users<<<USER_BLOCKS, 256, 0, stream>>>(fillc, colell, z0, z1);
    spmm_items<<<ITEM_BLOCKS, 256, 0, stream>>>(fillc, colell, z0, z1);
    spmm_users<<<USER_BLOCKS, 256, 0, stream>>>(fillc, colell, z1, z2);
    spmm_items<<<ITEM_BLOCKS, 256, 0, stream>>>(fillc, colell, z1, z2);

    bpr_loss<<<BPR_BLOCKS, 256, 0, stream>>>((const float4*)ue, (const float4*)ie,
                                             z1, z2, fillc, colell,
                                             usr, pos, neg, lacc, done, out);
}

// Round 16
// 163.560 us; speedup vs baseline: 1.0611x; 1.0611x over previous
//
#include <hip/hip_runtime.h>
#include <math.h>

#define N_USERS 40000
#define N_ITEMS 20000
#define NNODES  60000          // N_USERS + N_ITEMS; also the zero-pad row index
#define D       128
#define N_EDGES 320000
#define EPS_    1e-7f
#define BATCH   4096
#define STRIDE  64             // ELL row capacity (max degree ~45 for Poisson(16))
#define ZSCALE  256.0f         // fp8 storage scale; folded out in bpr
#define BPR_BLOCKS (BATCH / 8)             // 512: 4 waves x 2 elements each
#define FILL_GRPS  320                     // blocks per bucket
#define FILL_BLOCKS (8 * FILL_GRPS)        // 2560
#define INIT_BLOCKS (((NNODES + 1) * 16 + 255) / 256)  // 3751 (16 thr/row, +pad row)
#define FULL_BLOCKS (NNODES * 8 / 256)     // 1875 (8 threads per row)

typedef float vf2 __attribute__((ext_vector_type(2)));

// unpack 16 fp8 (e4m3) from uint4, accumulate into 8 packed-f32 pairs.
__device__ __forceinline__ void add_fp8x16v(vf2* a, uint4 t) {
    a[0] += __builtin_amdgcn_cvt_pk_f32_fp8(t.x, false);
    a[1] += __builtin_amdgcn_cvt_pk_f32_fp8(t.x, true);
    a[2] += __builtin_amdgcn_cvt_pk_f32_fp8(t.y, false);
    a[3] += __builtin_amdgcn_cvt_pk_f32_fp8(t.y, true);
    a[4] += __builtin_amdgcn_cvt_pk_f32_fp8(t.z, false);
    a[5] += __builtin_amdgcn_cvt_pk_f32_fp8(t.z, true);
    a[6] += __builtin_amdgcn_cvt_pk_f32_fp8(t.w, false);
    a[7] += __builtin_amdgcn_cvt_pk_f32_fp8(t.w, true);
}

// scale + clamp + pack 8 vf2 (16 f32) -> 16 fp8 (e4m3) in uint4
__device__ __forceinline__ uint4 pack_fp8x16v(const vf2* a, float w) {
    float v[16];
    #pragma unroll
    for (int k = 0; k < 8; ++k) {
        v[2 * k]     = fminf(fmaxf(w * a[k].x, -448.0f), 448.0f);
        v[2 * k + 1] = fminf(fmaxf(w * a[k].y, -448.0f), 448.0f);
    }
    int w0 = __builtin_amdgcn_cvt_pk_fp8_f32(v[0],  v[1],  0,  false);
    w0     = __builtin_amdgcn_cvt_pk_fp8_f32(v[2],  v[3],  w0, true);
    int w1 = __builtin_amdgcn_cvt_pk_fp8_f32(v[4],  v[5],  0,  false);
    w1     = __builtin_amdgcn_cvt_pk_fp8_f32(v[6],  v[7],  w1, true);
    int w2 = __builtin_amdgcn_cvt_pk_fp8_f32(v[8],  v[9],  0,  false);
    w2     = __builtin_amdgcn_cvt_pk_fp8_f32(v[10], v[11], w2, true);
    int w3 = __builtin_amdgcn_cvt_pk_fp8_f32(v[12], v[13], 0,  false);
    w3     = __builtin_amdgcn_cvt_pk_fp8_f32(v[14], v[15], w3, true);
    uint4 o; o.x = (unsigned)w0; o.y = (unsigned)w1;
    o.z = (unsigned)w2; o.w = (unsigned)w3;
    return o;
}

// gather 8 padded edges (2 int4 col loads, 8 uint4 gathers all in flight)
__device__ __forceinline__ void gather8(const int4* __restrict__ rcv, int t,
                                        const uint4* __restrict__ z, int sub,
                                        vf2* a) {
    int4 ca = rcv[2 * t], cb = rcv[2 * t + 1];
    uint4 t0 = z[(ca.x << 3) + sub];
    uint4 t1 = z[(ca.y << 3) + sub];
    uint4 t2 = z[(ca.z << 3) + sub];
    uint4 t3 = z[(ca.w << 3) + sub];
    uint4 t4 = z[(cb.x << 3) + sub];
    uint4 t5 = z[(cb.y << 3) + sub];
    uint4 t6 = z[(cb.z << 3) + sub];
    uint4 t7 = z[(cb.w << 3) + sub];
    add_fp8x16v(a, t0); add_fp8x16v(a, t1);
    add_fp8x16v(a, t2); add_fp8x16v(a, t3);
    add_fp8x16v(a, t4); add_fp8x16v(a, t5);
    add_fp8x16v(a, t6); add_fp8x16v(a, t7);
}

// ---- bucketed ELL fill (int2-vectorized); fillc ends holding the degree --
// users: bucket = u/10000 (0..3); items: bucket = 4 + (i-N_USERS)/5000.
// XCD-local scatter writes via blockIdx&7 round-robin (R11: -30us vs naive).
__global__ void fill_ell(const int2* __restrict__ au2, const int2* __restrict__ ai2,
                         int* __restrict__ fillc, int* __restrict__ colell) {
    const int bucket = blockIdx.x & 7;
    const int grp    = blockIdx.x >> 3;          // 0..FILL_GRPS-1
    const int NE2    = N_EDGES / 2;
    for (int i = grp * 256 + threadIdx.x; i < NE2; i += FILL_GRPS * 256) {
        int2 us = au2[i];
        int2 is = ai2[i];
        int u0 = us.x, i0 = N_USERS + is.x;
        int u1 = us.y, i1 = N_USERS + is.y;
        if (u0 / 10000 == bucket) {
            int pos = atomicAdd(&fillc[u0], 1);
            if (pos < STRIDE) colell[(u0 << 6) + pos] = i0;
        }
        if (u1 / 10000 == bucket) {
            int pos = atomicAdd(&fillc[u1], 1);
            if (pos < STRIDE) colell[(u1 << 6) + pos] = i1;
        }
        if (4 + (i0 - N_USERS) / 5000 == bucket) {
            int pos = atomicAdd(&fillc[i0], 1);
            if (pos < STRIDE) colell[(i0 << 6) + pos] = u0;
        }
        if (4 + (i1 - N_USERS) / 5000 == bucket) {
            int pos = atomicAdd(&fillc[i1], 1);
            if (pos < STRIDE) colell[(i1 << 6) + pos] = u1;
        }
    }
}

// ---- z0 init + colell 8-padding + zero-row init --------------------------
// 16 threads per row. Row NNODES is the shared zero row of z0/z1/z2.
__global__ void init_z(const int* __restrict__ fillc,
                       const float4* __restrict__ ue, const float4* __restrict__ ie,
                       uint2* __restrict__ z0, uint2* __restrict__ z1,
                       uint2* __restrict__ z2, int* __restrict__ colell) {
    int i   = blockIdx.x * 256 + threadIdx.x;
    if (i >= (NNODES + 1) * 16) return;
    int row = i >> 4;
    int sub = i & 15;
    if (row == NNODES) {                 // zero-pad row in all three buffers
        uint2 zz = make_uint2(0u, 0u);
        z0[i] = zz; z1[i] = zz; z2[i] = zz;
        return;
    }
    int e = fillc[row];
    if (sub == 0) {                      // pad colell row to a multiple of 8
        int ep = (e + 7) & ~7;
        for (int k = e; k < ep; ++k) colell[(row << 6) + k] = NNODES;
    }
    float w = rsqrtf((float)e + EPS_) * ZSCALE;
    float4 e0, e1;
    if (row < N_USERS) {
        int b4 = row * 32 + sub * 2;     // 32 float4 per row
        e0 = ue[b4]; e1 = ue[b4 + 1];
    } else {
        int b4 = (row - N_USERS) * 32 + sub * 2;
        e0 = ie[b4]; e1 = ie[b4 + 1];
    }
    float v[8] = { e0.x * w, e0.y * w, e0.z * w, e0.w * w,
                   e1.x * w, e1.y * w, e1.z * w, e1.w * w };
    float c[8];
    #pragma unroll
    for (int k = 0; k < 8; ++k) c[k] = fminf(fmaxf(v[k], -448.0f), 448.0f);
    int lo = __builtin_amdgcn_cvt_pk_fp8_f32(c[0], c[1], 0,  false);
    lo     = __builtin_amdgcn_cvt_pk_fp8_f32(c[2], c[3], lo, true);
    int hi = __builtin_amdgcn_cvt_pk_fp8_f32(c[4], c[5], 0,  false);
    hi     = __builtin_amdgcn_cvt_pk_fp8_f32(c[6], c[7], hi, true);
    z0[i] = make_uint2((unsigned)lo, (unsigned)hi);
}

// ---- SpMM, 8-lane subgroup rows, 8-edge padded chunks (mixed rows) -------
// R15 showed mixed-row single dispatch beats bipartite phase-split: the
// gather is transaction-rate bound; maximal grid co-scheduling wins.
__device__ __forceinline__ void spmm_body(const int* __restrict__ cnt,
                                          const int* __restrict__ colell,
                                          const uint4* __restrict__ z,
                                          uint4* __restrict__ znxt) {
    int tid = blockIdx.x * 256 + threadIdx.x;
    int row = tid >> 3;               // 32 rows per 256-thread block
    int sub = threadIdx.x & 7;
    int e = cnt[row];
    const int4* rcv = (const int4*)(colell + (row << 6));
    vf2 a[8];
    #pragma unroll
    for (int k = 0; k < 8; ++k) a[k] = (vf2)(0.0f);
    int nchunks = (e + 7) >> 3;
    for (int t = 0; t < nchunks; ++t) gather8(rcv, t, z, sub, a);
    float w = 1.0f / ((float)e + EPS_);   // dinv^2
    znxt[(row << 3) + sub] = pack_fp8x16v(a, w);
}

__global__ void spmm_L1(const int* __restrict__ cnt, const int* __restrict__ colell,
                        const uint4* __restrict__ z, uint4* __restrict__ znxt) {
    spmm_body(cnt, colell, z, znxt);
}
__global__ void spmm_L2(const int* __restrict__ cnt, const int* __restrict__ colell,
                        const uint4* __restrict__ z, uint4* __restrict__ znxt) {
    spmm_body(cnt, colell, z, znxt);
}

// ---- fused BPR loss: 2 elements per wave; u/p/n rows in 8-lane subgroups
// sg 0-2 = elem A's u/p/n, sg 4-6 = elem B's; sg 3/7 idle.
// zsum = dinv*ZSCALE*emb (f32 exact) + z1 + z2 + inline layer-3 from z2.
// diff = (sp/(du*dp) - sn/(du*dn)) / (16 * ZSCALE^2)
__global__ void bpr_loss(const float4* __restrict__ ue, const float4* __restrict__ ie,
                         const uint4* __restrict__ z1, const uint4* __restrict__ z2,
                         const int* __restrict__ cnt, const int* __restrict__ colell,
                         const int* __restrict__ user, const int* __restrict__ pos,
                         const int* __restrict__ neg,
                         float* __restrict__ lacc, int* __restrict__ done,
                         float* __restrict__ out) {
    __shared__ float s[8];
    int wave = (blockIdx.x * 256 + threadIdx.x) >> 6;   // global wave id
    int lane = threadIdx.x & 63;
    int sg   = lane >> 3;          // 0..7
    int sub  = lane & 7;
    int half = sg >> 2;            // 0 = elem A, 1 = elem B
    int sgl  = sg & 3;             // 0=u 1=p 2=n 3=idle
    int el   = wave * 2 + half;
    int u = user[el];
    int p = N_USERS + pos[el] - 1;  // 1-indexed items
    int n = N_USERS + neg[el] - 1;
    int node = (sgl == 1) ? p : (sgl == 2) ? n : u;
    float cnode = 0.0f;
    vf2 vals[8];
    #pragma unroll
    for (int k = 0; k < 8; ++k) vals[k] = (vf2)(0.0f);
    if (sgl < 3) {
        int e = cnt[node];
        cnode = (float)e;
        // layer-0 exact from f32 embeddings: 4 float4 per lane
        const float4* eb = (node < N_USERS) ? ue : ie;
        int b4 = ((node < N_USERS) ? node : node - N_USERS) * 32 + sub * 4;
        float4 e0 = eb[b4], e1 = eb[b4 + 1], e2 = eb[b4 + 2], e3 = eb[b4 + 3];
        float w0 = rsqrtf(cnode + EPS_) * ZSCALE;
        vals[0] = (vf2){w0 * e0.x, w0 * e0.y}; vals[1] = (vf2){w0 * e0.z, w0 * e0.w};
        vals[2] = (vf2){w0 * e1.x, w0 * e1.y}; vals[3] = (vf2){w0 * e1.z, w0 * e1.w};
        vals[4] = (vf2){w0 * e2.x, w0 * e2.y}; vals[5] = (vf2){w0 * e2.z, w0 * e2.w};
        vals[6] = (vf2){w0 * e3.x, w0 * e3.y}; vals[7] = (vf2){w0 * e3.z, w0 * e3.w};
        int o = (node << 3) + sub;
        add_fp8x16v(vals, z1[o]);
        add_fp8x16v(vals, z2[o]);
        // inline layer-3 gather from z2 (f32), 8-edge padded chunks
        const int4* rcv = (const int4*)(colell + (node << 6));
        vf2 a[8];
        #pragma unroll
        for (int k = 0; k < 8; ++k) a[k] = (vf2)(0.0f);
        int nchunks = (e + 7) >> 3;
        for (int t = 0; t < nchunks; ++t) gather8(rcv, t, z2, sub, a);
        float w2 = 1.0f / (cnode + EPS_);   // dinv^2
        #pragma unroll
        for (int k = 0; k < 8; ++k) vals[k] += w2 * a[k];
    }
    // pull the u-subgroup (sg0 / sg4) values into all subgroups of the half
    int usrc = sub | (lane & 32);
    float dotp = 0.0f;
    #pragma unroll
    for (int k = 0; k < 8; ++k) {
        dotp += __shfl(vals[k].x, usrc) * vals[k].x;
        dotp += __shfl(vals[k].y, usrc) * vals[k].y;
    }
    dotp += __shfl_down(dotp, 4, 8);
    dotp += __shfl_down(dotp, 2, 8);
    dotp += __shfl_down(dotp, 1, 8);
    // subgroup heads now hold: lane (lane&32)+8 -> u.p, +16 -> u.n
    float sp = __shfl(dotp, (lane & 32) + 8);
    float sn = __shfl(dotp, (lane & 32) + 16);
    float cu = __shfl(cnode, (lane & 32) + 0);
    float cp = __shfl(cnode, (lane & 32) + 8);
    float cn = __shfl(cnode, (lane & 32) + 16);
    if ((lane & 31) == 0) {   // lane 0 (elem A) and lane 32 (elem B)
        float du = rsqrtf(cu + EPS_), dp = rsqrtf(cp + EPS_), dn = rsqrtf(cn + EPS_);
        const float inv = 1.0f / (16.0f * ZSCALE * ZSCALE);
        float diff = (sp / (du * dp) - sn / (du * dn)) * inv;
        // log_sigmoid(x) = min(x,0) - log1p(exp(-|x|))
        s[(threadIdx.x >> 6) * 2 + half] =
            fminf(diff, 0.0f) - log1pf(expf(-fabsf(diff)));
    }
    __syncthreads();
    if (threadIdx.x == 0) {
        float t = s[0] + s[1] + s[2] + s[3] + s[4] + s[5] + s[6] + s[7];
        atomicAdd(lacc, t);
        __threadfence();
        int prev = atomicAdd(done, 1);
        if (prev == BPR_BLOCKS - 1) {
            float total = atomicAdd(lacc, 0.0f);   // coherent read
            out[0] = -total * (1.0f / (float)BATCH);
        }
    }
}

extern "C" void kernel_launch(void* const* d_in, const int* in_sizes, int n_in,
                              void* d_out, int out_size, void* d_ws, size_t ws_size,
                              hipStream_t stream) {
    const float* ue  = (const float*)d_in[0];
    const float* ie  = (const float*)d_in[1];
    const int*   au  = (const int*)d_in[2];
    const int*   ai  = (const int*)d_in[3];
    const int*   usr = (const int*)d_in[4];
    const int*   pos = (const int*)d_in[5];
    const int*   neg = (const int*)d_in[6];
    float*       out = (float*)d_out;

    const size_t ZQ4 = (size_t)(NNODES + 1) * 8;  // uint4 per z buffer (+zero row)

    // ws layout (16B-aligned chunks):
    // z0 | z1 | z2 (fp8, NNODES+1 rows) | [fillc | lacc | done | pad] | colell
    uint4* z0     = (uint4*)d_ws;
    uint4* z1     = z0 + ZQ4;
    uint4* z2     = z1 + ZQ4;
    int*   fillc  = (int*)(z2 + ZQ4);
    float* lacc   = (float*)(fillc + NNODES);
    int*   done   = (int*)(lacc + 1);
    int*   colell = (int*)(lacc + 4);             // NNODES * STRIDE ints

    // fillc + lacc + done zeroed in one shot
    hipMemsetAsync(fillc, 0, (NNODES + 4) * sizeof(int), stream);

    fill_ell<<<FILL_BLOCKS, 256, 0, stream>>>((const int2*)au, (const int2*)ai,
                                              fillc, colell);
    init_z<<<INIT_BLOCKS, 256, 0, stream>>>(fillc, (const float4*)ue,
                                            (const float4*)ie, (uint2*)z0,
                                            (uint2*)z1, (uint2*)z2, colell);

    spmm_L1<<<FULL_BLOCKS, 256, 0, stream>>>(fillc, colell, z0, z1);
    spmm_L2<<<FULL_BLOCKS, 256, 0, stream>>>(fillc, colell, z1, z2);

    bpr_loss<<<BPR_BLOCKS, 256, 0, stream>>>((const float4*)ue, (const float4*)ie,
                                             z1, z2, fillc, colell,
                                             usr, pos, neg, lacc, done, out);
}